// Round 6
// baseline (223.487 us; speedup 1.0000x reference)
//
#include <hip/hip_runtime.h>
#include <stdint.h>

// Problem constants (B=4, S=2048, H=1024, E=8, M=512, K=2, SM=1024, G=64)
#define T_TOK 8192
#define H_DIM 1024
#define M_DIM 512
#define SM_DIM 1024
#define E_NUM 8
#define S_SEQ 2048
#define G_DIM 64
#define NASSIGN 16384                      // T_TOK * 2
#define NSLOT (NASSIGN + E_NUM * 256)      // compact slots + per-expert 256-tile padding
#define MAX_TILES (NASSIGN / 256 + E_NUM)  // 72
#define NBLK_PLACE (NASSIGN / 256)         // 64

typedef float f32x4 __attribute__((ext_vector_type(4)));
typedef float f32x16 __attribute__((ext_vector_type(16)));
typedef short bf16x8 __attribute__((ext_vector_type(8)));

struct TileDesc { int base; int expert; int nrows; };

#define WAITCNT_VM6 asm volatile("s_waitcnt vmcnt(6)" ::: "memory")
#define WAITCNT_VM4 asm volatile("s_waitcnt vmcnt(4)" ::: "memory")
#define WAITCNT_VM2 asm volatile("s_waitcnt vmcnt(2)" ::: "memory")
#define WAITCNT_VM0 asm volatile("s_waitcnt vmcnt(0)" ::: "memory")
#define WAITCNT_LGKM0 asm volatile("s_waitcnt lgkmcnt(0)" ::: "memory")

static __device__ __forceinline__ ushort f2b(float f) {
  union { float f; uint32_t u; } a; a.f = f;
  uint32_t r = a.u + 0x7fffu + ((a.u >> 16) & 1u);  // RNE
  return (ushort)(r >> 16);
}
static __device__ __forceinline__ float b2f(ushort u) {
  union { uint32_t u; float f; } a; a.u = ((uint32_t)u) << 16;
  return a.f;
}
static __device__ __forceinline__ int imin(int a, int b) { return a < b ? a : b; }

// async global->LDS, 16B per lane; LDS dest = wave-uniform base + lane*16
static __device__ __forceinline__ void gll16(const void* g, void* l) {
  __builtin_amdgcn_global_load_lds(
      (const __attribute__((address_space(1))) void*)g,
      (__attribute__((address_space(3))) void*)l, 16, 0, 0);
}
// XCD-chunked bijective remap (nwg divisible by 8)
static __device__ __forceinline__ int xcd_remap(int wg, int nwg) {
  return (wg & 7) * (nwg >> 3) + (wg >> 3);
}

// ---------------- merged weight conversion (transpose+convert, 6 tensors) ----------------
__global__ void wcvt_kernel(const float* __restrict__ w_gate, const float* __restrict__ w_up,
                            const float* __restrict__ w_down, const float* __restrict__ sw_gate,
                            const float* __restrict__ sw_up, const float* __restrict__ sw_down,
                            ushort* __restrict__ wg_t, ushort* __restrict__ wu_t,
                            ushort* __restrict__ wd_t, ushort* __restrict__ swg_t,
                            ushort* __restrict__ swu_t, ushort* __restrict__ swd_t) {
  __shared__ float tile[32][33];
  int id = blockIdx.x;
  const float* src; ushort* dst; int R, C, t;
  if (id < 4096)        { src = w_gate;  dst = wg_t;  R = 1024; C = 512;  t = id; }
  else if (id < 8192)   { src = w_up;    dst = wu_t;  R = 1024; C = 512;  t = id - 4096; }
  else if (id < 12288)  { src = w_down;  dst = wd_t;  R = 512;  C = 1024; t = id - 8192; }
  else if (id < 13312)  { src = sw_gate; dst = swg_t; R = 1024; C = 1024; t = id - 12288; }
  else if (id < 14336)  { src = sw_up;   dst = swu_t; R = 1024; C = 1024; t = id - 13312; }
  else                  { src = sw_down; dst = swd_t; R = 1024; C = 1024; t = id - 14336; }
  int tc = C >> 5;
  int tpm = (R >> 5) * tc;
  int e = t / tpm, tt = t % tpm;
  int c0 = (tt % tc) * 32, r0 = (tt / tc) * 32;
  size_t bo = (size_t)e * R * C;
  src += bo; dst += bo;
#pragma unroll
  for (int i = 0; i < 4; ++i)
    tile[threadIdx.y + i * 8][threadIdx.x] =
        src[(size_t)(r0 + threadIdx.y + i * 8) * C + c0 + threadIdx.x];
  __syncthreads();
#pragma unroll
  for (int i = 0; i < 4; ++i)
    dst[(size_t)(c0 + threadIdx.y + i * 8) * R + r0 + threadIdx.x] =
        f2b(tile[threadIdx.x][threadIdx.y + i * 8]);
}

// ---------------- fused router: logits (incl. inline g-logits) + top-2 + x->bf16 ----------
__global__ __launch_bounds__(64) void router_kernel(
    const float* __restrict__ x, const float* __restrict__ wt, const float* __restrict__ g,
    const float* __restrict__ wgm, ushort* __restrict__ xb,
    int* __restrict__ tidx, float* __restrict__ tw) {
  int t = blockIdx.x;
  int lane = threadIdx.x;
  const float4* xr4 = (const float4*)x + (size_t)t * 256;
  ushort4* xb4 = (ushort4*)xb + (size_t)t * 256;
  float a[E_NUM];
#pragma unroll
  for (int e = 0; e < E_NUM; ++e) a[e] = 0.f;
#pragma unroll
  for (int j = 0; j < 4; ++j) {
    float4 v = xr4[lane + 64 * j];
    ushort4 o;
    o.x = f2b(v.x); o.y = f2b(v.y); o.z = f2b(v.z); o.w = f2b(v.w);
    xb4[lane + 64 * j] = o;
#pragma unroll
    for (int e = 0; e < E_NUM; ++e) {
      float4 wv = ((const float4*)(wt + (size_t)e * H_DIM))[lane + 64 * j];
      a[e] += v.x * wv.x + v.y * wv.y + v.z * wv.z + v.w * wv.w;
    }
  }
#pragma unroll
  for (int e = 0; e < E_NUM; ++e)
    for (int off = 32; off; off >>= 1) a[e] += __shfl_xor(a[e], off, 64);
  float lge = 0.f;
  int b = t / S_SEQ;
  if (lane < E_NUM) {
    const float* gv = g + b * G_DIM;
    const float* wv = wgm + lane * G_DIM;
    for (int i = 0; i < G_DIM; ++i) lge += gv[i] * wv[i];
  }
  float l[E_NUM];
#pragma unroll
  for (int e = 0; e < E_NUM; ++e) l[e] = 0.5f * (a[e] + __shfl(lge, e, 64));
  if (lane == 0) {
    int i1 = 0; float b1 = l[0];
#pragma unroll
    for (int e = 1; e < E_NUM; ++e) if (l[e] > b1) { b1 = l[e]; i1 = e; }
    int i2 = -1; float b2 = -1e30f;
#pragma unroll
    for (int e = 0; e < E_NUM; ++e) if (e != i1 && l[e] > b2) { b2 = l[e]; i2 = e; }
    float e2 = expf(b2 - b1);            // e1 = 1
    float inv = 1.f / (1.f + e2);
    tidx[t * 2] = i1; tidx[t * 2 + 1] = i2;
    tw[t * 2] = inv;  tw[t * 2 + 1] = e2 * inv;
  }
}

// per-256-chunk expert histogram
__global__ __launch_bounds__(256) void hist_kernel(const int* __restrict__ tidx,
                                                   int* __restrict__ bcount) {
  __shared__ int h[E_NUM];
  int tid = threadIdx.x;
  if (tid < E_NUM) h[tid] = 0;
  __syncthreads();
  atomicAdd(&h[tidx[blockIdx.x * 256 + tid]], 1);
  __syncthreads();
  if (tid < E_NUM) bcount[blockIdx.x * E_NUM + tid] = h[tid];
}

// one block: totals, expert offsets, tile descriptors (256-row), per-chunk offsets
__global__ __launch_bounds__(64) void scan2_kernel(
    const int* __restrict__ bcount, int* __restrict__ boffs, int* __restrict__ offs,
    TileDesc* __restrict__ desc, int* __restrict__ ndesc) {
  __shared__ int cnt[E_NUM];
  __shared__ int off_s[E_NUM];
  int lane = threadIdx.x;
  if (lane < E_NUM) {
    int s = 0;
    for (int b = 0; b < NBLK_PLACE; ++b) s += bcount[b * E_NUM + lane];
    cnt[lane] = s;
  }
  __syncthreads();
  if (lane == 0) {
    int o = 0, nd = 0;
    for (int e = 0; e < E_NUM; ++e) {
      off_s[e] = o;
      offs[e] = o;
      int n = cnt[e];
      for (int tb = 0; tb < n; tb += 256) {
        desc[nd].base = o + tb; desc[nd].expert = e;
        desc[nd].nrows = imin(n - tb, 256);
        ++nd;
      }
      o += n;
    }
    offs[E_NUM] = o;
    *ndesc = nd;
  }
  __syncthreads();
  if (lane < E_NUM) {
    int run = off_s[lane];
    for (int b = 0; b < NBLK_PLACE; ++b) {
      boffs[b * E_NUM + lane] = run;
      run += bcount[b * E_NUM + lane];
    }
  }
}

// stable parallel compaction: ballot rank within wave + LDS wave-count scan
__global__ __launch_bounds__(256) void place2_kernel(
    const int* __restrict__ tidx, const int* __restrict__ boffs,
    int* __restrict__ perm, int* __restrict__ slot_of) {
  __shared__ int wcnt[4][E_NUM];
  int tid = threadIdx.x, wv = tid >> 6, lane = tid & 63;
  int i = blockIdx.x * 256 + tid;
  int e = tidx[i];
  unsigned long long lower = (lane == 63) ? 0x7fffffffffffffffull : ((1ull << lane) - 1ull);
  int rank = 0;
#pragma unroll
  for (int ee = 0; ee < E_NUM; ++ee) {
    unsigned long long m = __ballot(e == ee);
    if (e == ee) rank = __popcll(m & lower);
    if (lane == 0) wcnt[wv][ee] = __popcll(m);
  }
  __syncthreads();
  int off = boffs[blockIdx.x * E_NUM + e];
  for (int w = 0; w < wv; ++w) off += wcnt[w][e];
  int pos = off + rank;
  perm[pos] = i >> 1;
  slot_of[i] = pos;
}

// ======== GEMM core: BM=256, BK=64, 8 waves, 4-phase K-tile, 32x32x16 MFMA ========
// A LDS piece qm: idx in [0,128) -> row (idx>>6)*128 + qm*64 + (idx&63); 64 ushort/idx,
//   stored as 8 chunks of 8 with chunk XOR (idx&7).
// B LDS piece n: idx in [0,128) -> weight-matrix row bbase_n + idx (dual: matrix n).
// A frag (32x32x16): row = lane&31, k = (lane>>5)*8 + reg; read idx = wr*64+m*32+(lane&31).
// B frag: col(weight row) = lane&31; read idx = wc*32+(lane&31).
// C/D: col = lane&31, row = (reg&3) + 8*(reg>>2) + 4*(lane>>5).
template <int DUAL>
static __device__ __forceinline__ void gemm_core8(
    const ushort* __restrict__ A, const ushort* __restrict__ B0,
    const ushort* __restrict__ B1, void* __restrict__ Out, int outf32,
    int Kd, int NdOut, int rowbase, int nrows, int n0,
    const int* __restrict__ perm, ushort* __restrict__ LDS) {
  int tid = threadIdx.x, wv = tid >> 6, lane = tid & 63;
  int wr = wv >> 2, wc = wv & 3;
  int l31 = lane & 31, hi = lane >> 5;
  int sid = lane >> 3, dch = lane & 7;

  // staging source pointers [piece][round]
  const ushort* apA[2][2];
  const ushort* apB[2][2];
#pragma unroll
  for (int qm = 0; qm < 2; ++qm)
#pragma unroll
    for (int k = 0; k < 2; ++k) {
      int idx = k * 64 + wv * 8 + sid;
      int gch = dch ^ (idx & 7);
      int grow = (idx >> 6) * 128 + qm * 64 + (idx & 63);
      grow = imin(grow, nrows - 1);
      int arow = perm ? perm[rowbase + grow] : rowbase + grow;
      apA[qm][k] = A + (size_t)arow * Kd + gch * 8;
    }
#pragma unroll
  for (int n = 0; n < 2; ++n)
#pragma unroll
    for (int k = 0; k < 2; ++k) {
      int idx = k * 64 + wv * 8 + sid;
      int gch = dch ^ (idx & 7);
      const ushort* src; int brow;
      if (DUAL) {
        src = n ? B1 : B0;
        brow = (n0 >> 1) + idx;
      } else {
        src = B0;
        brow = n0 + n * 128 + idx;
      }
      apB[n][k] = src + (size_t)brow * Kd + gch * 8;
    }

  auto stgA = [&](int qm, int k, int nd) {
    gll16(apA[qm][k], LDS + nd * 16384 + qm * 8192 + (k * 512 + wv * 64) * 8);
    apA[qm][k] += 64;
  };
  auto stgB = [&](int n, int k, int nd) {
    gll16(apB[n][k], LDS + 32768 + nd * 16384 + n * 8192 + (k * 512 + wv * 64) * 8);
    apB[n][k] += 64;
  };
  auto rdA = [&](int d, int qm, int m, int ks) -> bf16x8 {
    int idx = wr * 64 + m * 32 + l31;
    int ch = (ks * 2 + hi) ^ (idx & 7);
    return *(const bf16x8*)(LDS + d * 16384 + qm * 8192 + idx * 64 + ch * 8);
  };
  auto rdB = [&](int d, int n, int ks) -> bf16x8 {
    int idx = wc * 32 + l31;
    int ch = (ks * 2 + hi) ^ (idx & 7);
    return *(const bf16x8*)(LDS + 32768 + d * 16384 + n * 8192 + idx * 64 + ch * 8);
  };

  f32x16 acc[2][2][2];  // [qm][m][n]
#pragma unroll
  for (int qm = 0; qm < 2; ++qm)
#pragma unroll
    for (int m = 0; m < 2; ++m)
#pragma unroll
      for (int n = 0; n < 2; ++n) acc[qm][m][n] = (f32x16)(0.f);

  int nk = Kd >> 6;
  // prologue: stage tile 0 into dbuf 0, piece order A0,B0,B1,A1
  stgA(0, 0, 0); stgA(0, 1, 0);
  stgB(0, 0, 0); stgB(0, 1, 0);
  stgB(1, 0, 0); stgB(1, 1, 0);
  stgA(1, 0, 0); stgA(1, 1, 0);
  WAITCNT_VM4;  // A0,B0 landed
  __builtin_amdgcn_s_barrier();

  for (int t = 0; t < nk; ++t) {
    int cur = t & 1, nxt = cur ^ 1;
    bool hn = (t + 1 < nk);
    bf16x8 a0f[2][4], a1f[2][4], b0f[4], b1f[4];

    // ---- phase 0: read A0,B0; stage A0'; MFMA (qm0, n0)
#pragma unroll
    for (int m = 0; m < 2; ++m)
#pragma unroll
      for (int ks = 0; ks < 4; ++ks) a0f[m][ks] = rdA(cur, 0, m, ks);
#pragma unroll
    for (int ks = 0; ks < 4; ++ks) b0f[ks] = rdB(cur, 0, ks);
    if (hn) { stgA(0, 0, nxt); stgA(0, 1, nxt); WAITCNT_VM4; } else { WAITCNT_VM2; }
    WAITCNT_LGKM0;
    __builtin_amdgcn_s_barrier();
    __builtin_amdgcn_s_setprio(1);
#pragma unroll
    for (int m = 0; m < 2; ++m)
#pragma unroll
      for (int ks = 0; ks < 4; ++ks)
        acc[0][m][0] = __builtin_amdgcn_mfma_f32_32x32x16_bf16(a0f[m][ks], b0f[ks], acc[0][m][0], 0, 0, 0);
    __builtin_amdgcn_s_setprio(0);

    // ---- phase 1: read B1; stage B0'; MFMA (qm0, n1)
#pragma unroll
    for (int ks = 0; ks < 4; ++ks) b1f[ks] = rdB(cur, 1, ks);
    if (hn) { stgB(0, 0, nxt); stgB(0, 1, nxt); WAITCNT_VM4; } else { WAITCNT_VM0; }
    WAITCNT_LGKM0;
    __builtin_amdgcn_s_barrier();
    __builtin_amdgcn_s_setprio(1);
#pragma unroll
    for (int m = 0; m < 2; ++m)
#pragma unroll
      for (int ks = 0; ks < 4; ++ks)
        acc[0][m][1] = __builtin_amdgcn_mfma_f32_32x32x16_bf16(a0f[m][ks], b1f[ks], acc[0][m][1], 0, 0, 0);
    __builtin_amdgcn_s_setprio(0);

    // ---- phase 2: read A1; stage B1'; MFMA (qm1, n0)
#pragma unroll
    for (int m = 0; m < 2; ++m)
#pragma unroll
      for (int ks = 0; ks < 4; ++ks) a1f[m][ks] = rdA(cur, 1, m, ks);
    if (hn) { stgB(1, 0, nxt); stgB(1, 1, nxt); WAITCNT_VM6; }
    WAITCNT_LGKM0;
    __builtin_amdgcn_s_barrier();
    __builtin_amdgcn_s_setprio(1);
#pragma unroll
    for (int m = 0; m < 2; ++m)
#pragma unroll
      for (int ks = 0; ks < 4; ++ks)
        acc[1][m][0] = __builtin_amdgcn_mfma_f32_32x32x16_bf16(a1f[m][ks], b0f[ks], acc[1][m][0], 0, 0, 0);
    __builtin_amdgcn_s_setprio(0);

    // ---- phase 3: stage A1'; MFMA (qm1, n1)
    if (hn) { stgA(1, 0, nxt); stgA(1, 1, nxt); WAITCNT_VM4; }
    WAITCNT_LGKM0;
    __builtin_amdgcn_s_barrier();
    __builtin_amdgcn_s_setprio(1);
#pragma unroll
    for (int m = 0; m < 2; ++m)
#pragma unroll
      for (int ks = 0; ks < 4; ++ks)
        acc[1][m][1] = __builtin_amdgcn_mfma_f32_32x32x16_bf16(a1f[m][ks], b1f[ks], acc[1][m][1], 0, 0, 0);
    __builtin_amdgcn_s_setprio(0);
  }

  // epilogue: C/D col = lane&31, row = (reg&3) + 8*(reg>>2) + 4*(lane>>5)
  int rq = hi * 4;
#pragma unroll
  for (int qm = 0; qm < 2; ++qm)
#pragma unroll
    for (int m = 0; m < 2; ++m)
#pragma unroll
      for (int c = 0; c < 4; ++c)
#pragma unroll
        for (int r = 0; r < 4; ++r) {
          int row = wr * 128 + qm * 64 + m * 32 + c * 8 + r + rq;
          if (row < nrows) {
            if (DUAL) {
              float gv = acc[qm][m][0][c * 4 + r], uv = acc[qm][m][1][c * 4 + r];
              float hv = (gv >= 0.f ? gv : 0.01f * gv) * uv;
              int col = (n0 >> 1) + wc * 32 + l31;
              ((ushort*)Out)[(size_t)(rowbase + row) * NdOut + col] = f2b(hv);
            } else {
#pragma unroll
              for (int n = 0; n < 2; ++n) {
                int col = n0 + n * 128 + wc * 32 + l31;
                size_t o = (size_t)(rowbase + row) * NdOut + col;
                if (outf32) ((float*)Out)[o] = acc[qm][m][n][c * 4 + r];
                else ((ushort*)Out)[o] = f2b(acc[qm][m][n][c * 4 + r]);
              }
            }
          }
        }
}

// merged dual: blocks [0,256) shared-expert, [256,544) routed experts
__global__ __launch_bounds__(512) void gemm_dual_all(
    const ushort* __restrict__ xb, const ushort* __restrict__ swg,
    const ushort* __restrict__ swu, ushort* __restrict__ hsh,
    const ushort* __restrict__ wg, const ushort* __restrict__ wu,
    ushort* __restrict__ h_e, const int* __restrict__ perm,
    const TileDesc* __restrict__ desc, const int* __restrict__ ndesc) {
  __shared__ ushort LDS[65536];  // 128 KB
  int id = xcd_remap(blockIdx.x, gridDim.x);
  if (id < 256) {
    int mt = id >> 3, n0 = (id & 7) * 256;  // virt N = 2048
    gemm_core8<1>(xb, swg, swu, hsh, 0, H_DIM, SM_DIM, mt * 256, 256, n0, nullptr, LDS);
  } else {
    int rid = id - 256;
    int mt = rid >> 2, n0 = (rid & 3) * 256;  // virt N = 1024
    if (mt >= *ndesc) return;
    TileDesc d = desc[mt];
    size_t wo = (size_t)d.expert * M_DIM * H_DIM;
    gemm_core8<1>(xb, wg + wo, wu + wo, h_e, 0, H_DIM, M_DIM, d.base, d.nrows, n0, perm, LDS);
  }
}

// merged down: blocks [0,128) shared (f32 -> y), [128,416) routed (bf16 -> ye)
__global__ __launch_bounds__(512) void gemm_down_all(
    const ushort* __restrict__ hsh, const ushort* __restrict__ swd, float* __restrict__ y,
    const ushort* __restrict__ h_e, const ushort* __restrict__ wd, ushort* __restrict__ ye,
    const TileDesc* __restrict__ desc, const int* __restrict__ ndesc) {
  __shared__ ushort LDS[65536];  // 128 KB
  int id = xcd_remap(blockIdx.x, gridDim.x);
  if (id < 128) {
    int mt = id >> 2, n0 = (id & 3) * 256;
    gemm_core8<0>(hsh, swd, nullptr, (void*)y, 1, SM_DIM, H_DIM, mt * 256, 256, n0, nullptr, LDS);
  } else {
    int rid = id - 128;
    int mt = rid >> 2, n0 = (rid & 3) * 256;
    if (mt >= *ndesc) return;
    TileDesc d = desc[mt];
    gemm_core8<0>(h_e, wd + (size_t)d.expert * H_DIM * M_DIM, nullptr, (void*)ye, 0,
                  M_DIM, H_DIM, d.base, d.nrows, n0, nullptr, LDS);
  }
}

// y[t] += w0*ye[s0] + w1*ye[s1]   (y already holds shared-expert p)
__global__ void final_kernel(float* __restrict__ y, const ushort* __restrict__ ye,
                             const int* __restrict__ slot_of, const float* __restrict__ tw) {
  int i = blockIdx.x * 256 + threadIdx.x;  // T_TOK*H_DIM/4 threads
  int t = i >> 8;
  int c4 = (i & 255) * 4;
  int s0 = slot_of[t * 2], s1 = slot_of[t * 2 + 1];
  float w0 = tw[t * 2], w1 = tw[t * 2 + 1];
  float4 v = ((float4*)y)[i];
  ushort4 a = *(const ushort4*)(ye + (size_t)s0 * H_DIM + c4);
  ushort4 b = *(const ushort4*)(ye + (size_t)s1 * H_DIM + c4);
  v.x += w0 * b2f(a.x) + w1 * b2f(b.x);
  v.y += w0 * b2f(a.y) + w1 * b2f(b.y);
  v.z += w0 * b2f(a.z) + w1 * b2f(b.z);
  v.w += w0 * b2f(a.w) + w1 * b2f(b.w);
  ((float4*)y)[i] = v;
}

// ---------------- host ----------------
extern "C" void kernel_launch(void* const* d_in, const int* in_sizes, int n_in,
                              void* d_out, int out_size, void* d_ws, size_t ws_size,
                              hipStream_t stream) {
  const float* x       = (const float*)d_in[0];
  const float* g       = (const float*)d_in[1];
  const float* wt      = (const float*)d_in[2];
  const float* wg      = (const float*)d_in[3];
  const float* w_gate  = (const float*)d_in[4];
  const float* w_up    = (const float*)d_in[5];
  const float* w_down  = (const float*)d_in[6];
  const float* sw_gate = (const float*)d_in[7];
  const float* sw_up   = (const float*)d_in[8];
  const float* sw_down = (const float*)d_in[9];
  float* y = (float*)d_out;

  char* p = (char*)d_ws;
  auto alloc = [&](size_t bytes) -> char* {
    char* r = p;
    p += (bytes + 255) & ~(size_t)255;
    return r;
  };
  ushort* xb    = (ushort*)alloc((size_t)T_TOK * H_DIM * 2);
  ushort* wg_t  = (ushort*)alloc((size_t)E_NUM * M_DIM * H_DIM * 2);  // (E, M, H)
  ushort* wu_t  = (ushort*)alloc((size_t)E_NUM * M_DIM * H_DIM * 2);
  ushort* wd_t  = (ushort*)alloc((size_t)E_NUM * H_DIM * M_DIM * 2);  // (E, H, M)
  ushort* swg_t = (ushort*)alloc((size_t)SM_DIM * H_DIM * 2);         // (SM, H)
  ushort* swu_t = (ushort*)alloc((size_t)SM_DIM * H_DIM * 2);
  ushort* swd_t = (ushort*)alloc((size_t)H_DIM * SM_DIM * 2);         // (H, SM)
  int* tidx     = (int*)alloc(NASSIGN * 4);
  float* tw     = (float*)alloc(NASSIGN * 4);
  int* bcount   = (int*)alloc(NBLK_PLACE * E_NUM * 4);
  int* boffs    = (int*)alloc(NBLK_PLACE * E_NUM * 4);
  int* offs     = (int*)alloc((E_NUM + 1) * 4);
  int* ndesc    = (int*)alloc(4);
  int* perm     = (int*)alloc(NASSIGN * 4);
  int* slot_of  = (int*)alloc(NASSIGN * 4);
  TileDesc* desc = (TileDesc*)alloc(MAX_TILES * sizeof(TileDesc));
  ushort* h_e   = (ushort*)alloc((size_t)NSLOT * M_DIM * 2);
  ushort* hsh   = (ushort*)alloc((size_t)T_TOK * SM_DIM * 2);
  ushort* ye    = (ushort*)alloc((size_t)NSLOT * H_DIM * 2);
  (void)ws_size; (void)in_sizes; (void)n_in; (void)out_size;

  // merged weight conversions (1 launch) + fused router (x->bf16 + logits + top-2)
  dim3 tb(32, 8);
  wcvt_kernel<<<15360, tb, 0, stream>>>(w_gate, w_up, w_down, sw_gate, sw_up, sw_down,
                                        wg_t, wu_t, wd_t, swg_t, swu_t, swd_t);
  router_kernel<<<T_TOK, 64, 0, stream>>>(x, wt, g, wg, xb, tidx, tw);
  hist_kernel<<<NBLK_PLACE, 256, 0, stream>>>(tidx, bcount);
  scan2_kernel<<<1, 64, 0, stream>>>(bcount, boffs, offs, desc, ndesc);
  place2_kernel<<<NBLK_PLACE, 256, 0, stream>>>(tidx, boffs, perm, slot_of);

  // fused gate/up duals (shared + routed in one launch)
  gemm_dual_all<<<256 + MAX_TILES * 4, 512, 0, stream>>>(
      xb, swg_t, swu_t, hsh, wg_t, wu_t, h_e, perm, desc, ndesc);
  // down projections (shared -> y f32, routed -> ye bf16, one launch)
  gemm_down_all<<<128 + MAX_TILES * 4, 512, 0, stream>>>(
      hsh, swd_t, y, h_e, wd_t, ye, desc, ndesc);

  // combine
  final_kernel<<<T_TOK * H_DIM / 4 / 256, 256, 0, stream>>>(y, ye, slot_of, tw);
}

// Round 7
// 207.479 us; speedup vs baseline: 1.0772x; 1.0772x over previous
//
#include <hip/hip_runtime.h>
#include <stdint.h>

// Problem constants (B=4, S=2048, H=1024, E=8, M=512, K=2, SM=1024, G=64)
#define T_TOK 8192
#define H_DIM 1024
#define M_DIM 512
#define SM_DIM 1024
#define E_NUM 8
#define S_SEQ 2048
#define G_DIM 64
#define NASSIGN 16384                      // T_TOK * 2
#define NSLOT (NASSIGN + E_NUM * 256)      // compact slots + per-expert 256-tile padding
#define MAX_TILES (NASSIGN / 256 + E_NUM)  // 72
#define NBLK_PLACE (NASSIGN / 256)         // 64

typedef float f32x4 __attribute__((ext_vector_type(4)));
typedef short bf16x8 __attribute__((ext_vector_type(8)));

struct TileDesc { int base; int expert; int nrows; };

#define WAITCNT_VM6 asm volatile("s_waitcnt vmcnt(6)" ::: "memory")
#define WAITCNT_VM4 asm volatile("s_waitcnt vmcnt(4)" ::: "memory")
#define WAITCNT_VM2 asm volatile("s_waitcnt vmcnt(2)" ::: "memory")
#define WAITCNT_VM0 asm volatile("s_waitcnt vmcnt(0)" ::: "memory")
#define WAITCNT_LGKM0 asm volatile("s_waitcnt lgkmcnt(0)" ::: "memory")

static __device__ __forceinline__ ushort f2b(float f) {
  union { float f; uint32_t u; } a; a.f = f;
  uint32_t r = a.u + 0x7fffu + ((a.u >> 16) & 1u);  // RNE
  return (ushort)(r >> 16);
}
static __device__ __forceinline__ float b2f(ushort u) {
  union { uint32_t u; float f; } a; a.u = ((uint32_t)u) << 16;
  return a.f;
}
static __device__ __forceinline__ int imin(int a, int b) { return a < b ? a : b; }

// async global->LDS, 16B per lane; LDS dest = wave-uniform base + lane*16
static __device__ __forceinline__ void gll16(const void* g, void* l) {
  __builtin_amdgcn_global_load_lds(
      (const __attribute__((address_space(1))) void*)g,
      (__attribute__((address_space(3))) void*)l, 16, 0, 0);
}
// XCD-chunked bijective remap (nwg divisible by 8)
static __device__ __forceinline__ int xcd_remap(int wg, int nwg) {
  return (wg & 7) * (nwg >> 3) + (wg >> 3);
}

// ---------------- prep: merged weight transpose/convert + fused router ----------------
// blocks [0, 15360): 32x32 transpose tiles over 6 weight tensors
// blocks [15360, 17408): router, 4 tokens per block (1 wave each):
//   logits (x@wt^T + g@wg^T inline), top-2 softmax weights, x -> bf16
__global__ __launch_bounds__(256) void prep_kernel(
    const float* __restrict__ x, const float* __restrict__ wt, const float* __restrict__ g,
    const float* __restrict__ wgm,
    const float* __restrict__ w_gate, const float* __restrict__ w_up,
    const float* __restrict__ w_down, const float* __restrict__ sw_gate,
    const float* __restrict__ sw_up, const float* __restrict__ sw_down,
    ushort* __restrict__ wg_t, ushort* __restrict__ wu_t,
    ushort* __restrict__ wd_t, ushort* __restrict__ swg_t,
    ushort* __restrict__ swu_t, ushort* __restrict__ swd_t,
    ushort* __restrict__ xb, int* __restrict__ tidx, float* __restrict__ tw) {
  __shared__ float tile[32][33];
  int id = blockIdx.x;
  if (id < 15360) {
    int tx = threadIdx.x & 31, ty = threadIdx.x >> 5;
    const float* src; ushort* dst; int R, C, t;
    if (id < 4096)        { src = w_gate;  dst = wg_t;  R = 1024; C = 512;  t = id; }
    else if (id < 8192)   { src = w_up;    dst = wu_t;  R = 1024; C = 512;  t = id - 4096; }
    else if (id < 12288)  { src = w_down;  dst = wd_t;  R = 512;  C = 1024; t = id - 8192; }
    else if (id < 13312)  { src = sw_gate; dst = swg_t; R = 1024; C = 1024; t = id - 12288; }
    else if (id < 14336)  { src = sw_up;   dst = swu_t; R = 1024; C = 1024; t = id - 13312; }
    else                  { src = sw_down; dst = swd_t; R = 1024; C = 1024; t = id - 14336; }
    int tc = C >> 5;
    int tpm = (R >> 5) * tc;
    int e = t / tpm, tt = t % tpm;
    int c0 = (tt % tc) * 32, r0 = (tt / tc) * 32;
    size_t bo = (size_t)e * R * C;
    src += bo; dst += bo;
#pragma unroll
    for (int i = 0; i < 4; ++i)
      tile[ty + i * 8][tx] = src[(size_t)(r0 + ty + i * 8) * C + c0 + tx];
    __syncthreads();
#pragma unroll
    for (int i = 0; i < 4; ++i)
      dst[(size_t)(c0 + ty + i * 8) * R + r0 + tx] = f2b(tile[tx][ty + i * 8]);
    return;
  }
  // ---- router ----
  int id2 = id - 15360;
  int wv = threadIdx.x >> 6, lane = threadIdx.x & 63;
  int t = id2 * 4 + wv;
  const float4* xr4 = (const float4*)x + (size_t)t * 256;
  ushort4* xb4 = (ushort4*)xb + (size_t)t * 256;
  float a[E_NUM];
#pragma unroll
  for (int e = 0; e < E_NUM; ++e) a[e] = 0.f;
#pragma unroll
  for (int j = 0; j < 4; ++j) {
    float4 v = xr4[lane + 64 * j];
    ushort4 o;
    o.x = f2b(v.x); o.y = f2b(v.y); o.z = f2b(v.z); o.w = f2b(v.w);
    xb4[lane + 64 * j] = o;
#pragma unroll
    for (int e = 0; e < E_NUM; ++e) {
      float4 wv4 = ((const float4*)(wt + (size_t)e * H_DIM))[lane + 64 * j];
      a[e] += v.x * wv4.x + v.y * wv4.y + v.z * wv4.z + v.w * wv4.w;
    }
  }
#pragma unroll
  for (int e = 0; e < E_NUM; ++e)
    for (int off = 32; off; off >>= 1) a[e] += __shfl_xor(a[e], off, 64);
  float lge = 0.f;
  int b = t / S_SEQ;
  if (lane < E_NUM) {
    const float* gv = g + b * G_DIM;
    const float* wv2 = wgm + lane * G_DIM;
    for (int i = 0; i < G_DIM; ++i) lge += gv[i] * wv2[i];
  }
  float l[E_NUM];
#pragma unroll
  for (int e = 0; e < E_NUM; ++e) l[e] = 0.5f * (a[e] + __shfl(lge, e, 64));
  if (lane == 0) {
    int i1 = 0; float b1 = l[0];
#pragma unroll
    for (int e = 1; e < E_NUM; ++e) if (l[e] > b1) { b1 = l[e]; i1 = e; }
    int i2 = -1; float b2 = -1e30f;
#pragma unroll
    for (int e = 0; e < E_NUM; ++e) if (e != i1 && l[e] > b2) { b2 = l[e]; i2 = e; }
    float e2 = expf(b2 - b1);            // e1 = 1
    float inv = 1.f / (1.f + e2);
    tidx[t * 2] = i1; tidx[t * 2 + 1] = i2;
    tw[t * 2] = inv;  tw[t * 2 + 1] = e2 * inv;
  }
}

// per-256-chunk expert histogram
__global__ __launch_bounds__(256) void hist_kernel(const int* __restrict__ tidx,
                                                   int* __restrict__ bcount) {
  __shared__ int h[E_NUM];
  int tid = threadIdx.x;
  if (tid < E_NUM) h[tid] = 0;
  __syncthreads();
  atomicAdd(&h[tidx[blockIdx.x * 256 + tid]], 1);
  __syncthreads();
  if (tid < E_NUM) bcount[blockIdx.x * E_NUM + tid] = h[tid];
}

// one block: totals, expert offsets, tile descriptors (256-row), per-chunk offsets
__global__ __launch_bounds__(64) void scan2_kernel(
    const int* __restrict__ bcount, int* __restrict__ boffs, int* __restrict__ offs,
    TileDesc* __restrict__ desc, int* __restrict__ ndesc) {
  __shared__ int cnt[E_NUM];
  __shared__ int off_s[E_NUM];
  int lane = threadIdx.x;
  if (lane < E_NUM) {
    int s = 0;
    for (int b = 0; b < NBLK_PLACE; ++b) s += bcount[b * E_NUM + lane];
    cnt[lane] = s;
  }
  __syncthreads();
  if (lane == 0) {
    int o = 0, nd = 0;
    for (int e = 0; e < E_NUM; ++e) {
      off_s[e] = o;
      offs[e] = o;
      int n = cnt[e];
      for (int tb = 0; tb < n; tb += 256) {
        desc[nd].base = o + tb; desc[nd].expert = e;
        desc[nd].nrows = imin(n - tb, 256);
        ++nd;
      }
      o += n;
    }
    offs[E_NUM] = o;
    *ndesc = nd;
  }
  __syncthreads();
  if (lane < E_NUM) {
    int run = off_s[lane];
    for (int b = 0; b < NBLK_PLACE; ++b) {
      boffs[b * E_NUM + lane] = run;
      run += bcount[b * E_NUM + lane];
    }
  }
}

// stable parallel compaction: ballot rank within wave + LDS wave-count scan
__global__ __launch_bounds__(256) void place2_kernel(
    const int* __restrict__ tidx, const int* __restrict__ boffs,
    int* __restrict__ perm, int* __restrict__ slot_of) {
  __shared__ int wcnt[4][E_NUM];
  int tid = threadIdx.x, wv = tid >> 6, lane = tid & 63;
  int i = blockIdx.x * 256 + tid;
  int e = tidx[i];
  unsigned long long lower = (lane == 63) ? 0x7fffffffffffffffull : ((1ull << lane) - 1ull);
  int rank = 0;
#pragma unroll
  for (int ee = 0; ee < E_NUM; ++ee) {
    unsigned long long m = __ballot(e == ee);
    if (e == ee) rank = __popcll(m & lower);
    if (lane == 0) wcnt[wv][ee] = __popcll(m);
  }
  __syncthreads();
  int off = boffs[blockIdx.x * E_NUM + e];
  for (int w = 0; w < wv; ++w) off += wcnt[w][e];
  int pos = off + rank;
  perm[pos] = i >> 1;
  slot_of[i] = pos;
}

// ======== GEMM core: BM=256, BN=256(virt), BK=64, 8 waves, 4-phase K-tile ========
// (round-5 verified core, 16x16x32 MFMA)
template <int DUAL>
static __device__ __forceinline__ void gemm_core8(
    const ushort* __restrict__ A, const ushort* __restrict__ B0,
    const ushort* __restrict__ B1, void* __restrict__ Out, int outf32,
    int Kd, int NdOut, int rowbase, int nrows, int n0,
    const int* __restrict__ perm, ushort* __restrict__ LDS) {
  int tid = threadIdx.x, wv = tid >> 6, lane = tid & 63;
  int wr = wv >> 2, wc = wv & 3;
  int lr = lane & 15, cg = lane >> 4;
  int sid = lane >> 3, dch = lane & 7;

  // staging source pointers [piece][round]
  const ushort* apA[2][2];
  const ushort* apB[2][2];
#pragma unroll
  for (int qm = 0; qm < 2; ++qm)
#pragma unroll
    for (int k = 0; k < 2; ++k) {
      int idx = k * 64 + wv * 8 + sid;
      int gch = dch ^ (idx & 7);
      int grow = (idx >> 6) * 128 + qm * 64 + (idx & 63);
      grow = imin(grow, nrows - 1);
      int arow = perm ? perm[rowbase + grow] : rowbase + grow;
      apA[qm][k] = A + (size_t)arow * Kd + gch * 8;
    }
#pragma unroll
  for (int qn = 0; qn < 2; ++qn)
#pragma unroll
    for (int k = 0; k < 2; ++k) {
      int idx = k * 64 + wv * 8 + sid;
      int gch = dch ^ (idx & 7);
      int vrow = n0 + (idx >> 5) * 64 + qn * 32 + (idx & 31);
      const ushort* src; int brow;
      if (DUAL) {
        src = ((vrow >> 4) & 1) ? B1 : B0;
        brow = (vrow >> 5) * 16 + (vrow & 15);
      } else {
        src = B0; brow = vrow;
      }
      apB[qn][k] = src + (size_t)brow * Kd + gch * 8;
    }

  auto stgA = [&](int qm, int k, int nd) {
    gll16(apA[qm][k], LDS + nd * 16384 + qm * 8192 + (k * 512 + wv * 64) * 8);
    apA[qm][k] += 64;
  };
  auto stgB = [&](int qn, int k, int nd) {
    gll16(apB[qn][k], LDS + 32768 + nd * 16384 + qn * 8192 + (k * 512 + wv * 64) * 8);
    apB[qn][k] += 64;
  };
  auto rdA = [&](int d, int qm, int m, int kk) -> bf16x8 {
    int idx = wr * 64 + m * 16 + lr;
    int ch = (kk * 4 + cg) ^ (idx & 7);
    return *(const bf16x8*)(LDS + d * 16384 + qm * 8192 + idx * 64 + ch * 8);
  };
  auto rdB = [&](int d, int qn, int n, int kk) -> bf16x8 {
    int idx = wc * 32 + n * 16 + lr;
    int ch = (kk * 4 + cg) ^ (idx & 7);
    return *(const bf16x8*)(LDS + 32768 + d * 16384 + qn * 8192 + idx * 64 + ch * 8);
  };

  f32x4 acc[2][2][4][2];
#pragma unroll
  for (int qm = 0; qm < 2; ++qm)
#pragma unroll
    for (int qn = 0; qn < 2; ++qn)
#pragma unroll
      for (int m = 0; m < 4; ++m)
#pragma unroll
        for (int n = 0; n < 2; ++n) acc[qm][qn][m][n] = (f32x4){0.f, 0.f, 0.f, 0.f};

  int nk = Kd >> 6;
  // prologue: stage tile 0 into dbuf 0, piece order A0,B0,B1,A1
  stgA(0, 0, 0); stgA(0, 1, 0);
  stgB(0, 0, 0); stgB(0, 1, 0);
  stgB(1, 0, 0); stgB(1, 1, 0);
  stgA(1, 0, 0); stgA(1, 1, 0);
  WAITCNT_VM4;  // A0,B0 landed
  __builtin_amdgcn_s_barrier();

  for (int t = 0; t < nk; ++t) {
    int cur = t & 1, nxt = cur ^ 1;
    bool hn = (t + 1 < nk);
    bf16x8 a0f[4][2], a1f[4][2], b0f[2][2], b1f[2][2];

    // ---- phase 0: read A0,B0; stage A0'; MFMA Q(0,0)
#pragma unroll
    for (int m = 0; m < 4; ++m) { a0f[m][0] = rdA(cur, 0, m, 0); a0f[m][1] = rdA(cur, 0, m, 1); }
#pragma unroll
    for (int n = 0; n < 2; ++n) { b0f[n][0] = rdB(cur, 0, n, 0); b0f[n][1] = rdB(cur, 0, n, 1); }
    if (hn) { stgA(0, 0, nxt); stgA(0, 1, nxt); WAITCNT_VM4; } else { WAITCNT_VM2; }
    WAITCNT_LGKM0;
    __builtin_amdgcn_s_barrier();
    __builtin_amdgcn_s_setprio(1);
#pragma unroll
    for (int m = 0; m < 4; ++m)
#pragma unroll
      for (int n = 0; n < 2; ++n) {
        acc[0][0][m][n] = __builtin_amdgcn_mfma_f32_16x16x32_bf16(a0f[m][0], b0f[n][0], acc[0][0][m][n], 0, 0, 0);
        acc[0][0][m][n] = __builtin_amdgcn_mfma_f32_16x16x32_bf16(a0f[m][1], b0f[n][1], acc[0][0][m][n], 0, 0, 0);
      }
    __builtin_amdgcn_s_setprio(0);

    // ---- phase 1: read B1; stage B0'; MFMA Q(0,1)
#pragma unroll
    for (int n = 0; n < 2; ++n) { b1f[n][0] = rdB(cur, 1, n, 0); b1f[n][1] = rdB(cur, 1, n, 1); }
    if (hn) { stgB(0, 0, nxt); stgB(0, 1, nxt); WAITCNT_VM4; } else { WAITCNT_VM0; }
    WAITCNT_LGKM0;
    __builtin_amdgcn_s_barrier();
    __builtin_amdgcn_s_setprio(1);
#pragma unroll
    for (int m = 0; m < 4; ++m)
#pragma unroll
      for (int n = 0; n < 2; ++n) {
        acc[0][1][m][n] = __builtin_amdgcn_mfma_f32_16x16x32_bf16(a0f[m][0], b1f[n][0], acc[0][1][m][n], 0, 0, 0);
        acc[0][1][m][n] = __builtin_amdgcn_mfma_f32_16x16x32_bf16(a0f[m][1], b1f[n][1], acc[0][1][m][n], 0, 0, 0);
      }
    __builtin_amdgcn_s_setprio(0);

    // ---- phase 2: read A1; stage B1'; MFMA Q(1,0)
#pragma unroll
    for (int m = 0; m < 4; ++m) { a1f[m][0] = rdA(cur, 1, m, 0); a1f[m][1] = rdA(cur, 1, m, 1); }
    if (hn) { stgB(1, 0, nxt); stgB(1, 1, nxt); WAITCNT_VM6; }
    WAITCNT_LGKM0;
    __builtin_amdgcn_s_barrier();
    __builtin_amdgcn_s_setprio(1);
#pragma unroll
    for (int m = 0; m < 4; ++m)
#pragma unroll
      for (int n = 0; n < 2; ++n) {
        acc[1][0][m][n] = __builtin_amdgcn_mfma_f32_16x16x32_bf16(a1f[m][0], b0f[n][0], acc[1][0][m][n], 0, 0, 0);
        acc[1][0][m][n] = __builtin_amdgcn_mfma_f32_16x16x32_bf16(a1f[m][1], b0f[n][1], acc[1][0][m][n], 0, 0, 0);
      }
    __builtin_amdgcn_s_setprio(0);

    // ---- phase 3: stage A1'; MFMA Q(1,1)
    if (hn) { stgA(1, 0, nxt); stgA(1, 1, nxt); WAITCNT_VM4; }
    WAITCNT_LGKM0;
    __builtin_amdgcn_s_barrier();
    __builtin_amdgcn_s_setprio(1);
#pragma unroll
    for (int m = 0; m < 4; ++m)
#pragma unroll
      for (int n = 0; n < 2; ++n) {
        acc[1][1][m][n] = __builtin_amdgcn_mfma_f32_16x16x32_bf16(a1f[m][0], b1f[n][0], acc[1][1][m][n], 0, 0, 0);
        acc[1][1][m][n] = __builtin_amdgcn_mfma_f32_16x16x32_bf16(a1f[m][1], b1f[n][1], acc[1][1][m][n], 0, 0, 0);
      }
    __builtin_amdgcn_s_setprio(0);
  }

  // epilogue (C/D layout: col=lane&15, row=(lane>>4)*4+reg)
#pragma unroll
  for (int qm = 0; qm < 2; ++qm)
#pragma unroll
    for (int qn = 0; qn < 2; ++qn)
#pragma unroll
      for (int m = 0; m < 4; ++m)
#pragma unroll
        for (int r = 0; r < 4; ++r) {
          int row = wr * 128 + qm * 64 + m * 16 + cg * 4 + r;
          if (row < nrows) {
            if (DUAL) {
              float gv = acc[qm][qn][m][0][r], uv = acc[qm][qn][m][1][r];
              float hv = (gv >= 0.f ? gv : 0.01f * gv) * uv;
              int col = ((n0 >> 5) + wc * 2 + qn) * 16 + lr;
              ((ushort*)Out)[(size_t)(rowbase + row) * NdOut + col] = f2b(hv);
            } else {
#pragma unroll
              for (int n = 0; n < 2; ++n) {
                int col = n0 + wc * 64 + qn * 32 + n * 16 + lr;
                size_t o = (size_t)(rowbase + row) * NdOut + col;
                if (outf32) ((float*)Out)[o] = acc[qm][qn][m][n][r];
                else ((ushort*)Out)[o] = f2b(acc[qm][qn][m][n][r]);
              }
            }
          }
        }
}

// merged dual: blocks [0,256) shared-expert, [256,544) routed experts
__global__ __launch_bounds__(512) void gemm_dual_all(
    const ushort* __restrict__ xb, const ushort* __restrict__ swg,
    const ushort* __restrict__ swu, ushort* __restrict__ hsh,
    const ushort* __restrict__ wg, const ushort* __restrict__ wu,
    ushort* __restrict__ h_e, const int* __restrict__ perm,
    const TileDesc* __restrict__ desc, const int* __restrict__ ndesc) {
  __shared__ ushort LDS[65536];  // 128 KB
  int id = xcd_remap(blockIdx.x, gridDim.x);
  if (id < 256) {
    int mt = id >> 3, n0 = (id & 7) * 256;
    gemm_core8<1>(xb, swg, swu, hsh, 0, H_DIM, SM_DIM, mt * 256, 256, n0, nullptr, LDS);
  } else {
    int rid = id - 256;
    int mt = rid >> 2, n0 = (rid & 3) * 256;
    if (mt >= *ndesc) return;
    TileDesc d = desc[mt];
    size_t wo = (size_t)d.expert * M_DIM * H_DIM;
    gemm_core8<1>(xb, wg + wo, wu + wo, h_e, 0, H_DIM, M_DIM, d.base, d.nrows, n0, perm, LDS);
  }
}

// merged down: blocks [0,128) shared (bf16 -> ysh), [128,416) routed (bf16 -> ye)
__global__ __launch_bounds__(512) void gemm_down_all(
    const ushort* __restrict__ hsh, const ushort* __restrict__ swd, ushort* __restrict__ ysh,
    const ushort* __restrict__ h_e, const ushort* __restrict__ wd, ushort* __restrict__ ye,
    const TileDesc* __restrict__ desc, const int* __restrict__ ndesc) {
  __shared__ ushort LDS[65536];  // 128 KB
  int id = xcd_remap(blockIdx.x, gridDim.x);
  if (id < 128) {
    int mt = id >> 2, n0 = (id & 3) * 256;
    gemm_core8<0>(hsh, swd, nullptr, (void*)ysh, 0, SM_DIM, H_DIM, mt * 256, 256, n0, nullptr, LDS);
  } else {
    int rid = id - 128;
    int mt = rid >> 2, n0 = (rid & 3) * 256;
    if (mt >= *ndesc) return;
    TileDesc d = desc[mt];
    gemm_core8<0>(h_e, wd + (size_t)d.expert * H_DIM * M_DIM, nullptr, (void*)ye, 0,
                  M_DIM, H_DIM, d.base, d.nrows, n0, nullptr, LDS);
  }
}

// y[t] = ysh[t] + w0*ye[s0] + w1*ye[s1]  (grid-stride, 2048 blocks)
__global__ __launch_bounds__(256) void final_kernel(
    float* __restrict__ y, const ushort* __restrict__ ysh, const ushort* __restrict__ ye,
    const int* __restrict__ slot_of, const float* __restrict__ tw) {
  for (int i = blockIdx.x * 256 + threadIdx.x; i < T_TOK * H_DIM / 4; i += 2048 * 256) {
    int t = i >> 8;
    int c4 = (i & 255) * 4;
    int s0 = slot_of[t * 2], s1 = slot_of[t * 2 + 1];
    float w0 = tw[t * 2], w1 = tw[t * 2 + 1];
    ushort4 pp = *(const ushort4*)(ysh + (size_t)t * H_DIM + c4);
    ushort4 a = *(const ushort4*)(ye + (size_t)s0 * H_DIM + c4);
    ushort4 b = *(const ushort4*)(ye + (size_t)s1 * H_DIM + c4);
    float4 v;
    v.x = b2f(pp.x) + w0 * b2f(a.x) + w1 * b2f(b.x);
    v.y = b2f(pp.y) + w0 * b2f(a.y) + w1 * b2f(b.y);
    v.z = b2f(pp.z) + w0 * b2f(a.z) + w1 * b2f(b.z);
    v.w = b2f(pp.w) + w0 * b2f(a.w) + w1 * b2f(b.w);
    ((float4*)y)[i] = v;
  }
}

// ---------------- host ----------------
extern "C" void kernel_launch(void* const* d_in, const int* in_sizes, int n_in,
                              void* d_out, int out_size, void* d_ws, size_t ws_size,
                              hipStream_t stream) {
  const float* x       = (const float*)d_in[0];
  const float* g       = (const float*)d_in[1];
  const float* wt      = (const float*)d_in[2];
  const float* wg      = (const float*)d_in[3];
  const float* w_gate  = (const float*)d_in[4];
  const float* w_up    = (const float*)d_in[5];
  const float* w_down  = (const float*)d_in[6];
  const float* sw_gate = (const float*)d_in[7];
  const float* sw_up   = (const float*)d_in[8];
  const float* sw_down = (const float*)d_in[9];
  float* y = (float*)d_out;

  char* p = (char*)d_ws;
  auto alloc = [&](size_t bytes) -> char* {
    char* r = p;
    p += (bytes + 255) & ~(size_t)255;
    return r;
  };
  ushort* xb    = (ushort*)alloc((size_t)T_TOK * H_DIM * 2);
  ushort* wg_t  = (ushort*)alloc((size_t)E_NUM * M_DIM * H_DIM * 2);  // (E, M, H)
  ushort* wu_t  = (ushort*)alloc((size_t)E_NUM * M_DIM * H_DIM * 2);
  ushort* wd_t  = (ushort*)alloc((size_t)E_NUM * H_DIM * M_DIM * 2);  // (E, H, M)
  ushort* swg_t = (ushort*)alloc((size_t)SM_DIM * H_DIM * 2);         // (SM, H)
  ushort* swu_t = (ushort*)alloc((size_t)SM_DIM * H_DIM * 2);
  ushort* swd_t = (ushort*)alloc((size_t)H_DIM * SM_DIM * 2);         // (H, SM)
  int* tidx     = (int*)alloc(NASSIGN * 4);
  float* tw     = (float*)alloc(NASSIGN * 4);
  int* bcount   = (int*)alloc(NBLK_PLACE * E_NUM * 4);
  int* boffs    = (int*)alloc(NBLK_PLACE * E_NUM * 4);
  int* offs     = (int*)alloc((E_NUM + 1) * 4);
  int* ndesc    = (int*)alloc(4);
  int* perm     = (int*)alloc(NASSIGN * 4);
  int* slot_of  = (int*)alloc(NASSIGN * 4);
  TileDesc* desc = (TileDesc*)alloc(MAX_TILES * sizeof(TileDesc));
  ushort* h_e   = (ushort*)alloc((size_t)NSLOT * M_DIM * 2);
  ushort* hsh   = (ushort*)alloc((size_t)T_TOK * SM_DIM * 2);
  ushort* ye    = (ushort*)alloc((size_t)NSLOT * H_DIM * 2);
  ushort* ysh   = (ushort*)alloc((size_t)T_TOK * H_DIM * 2);
  (void)ws_size; (void)in_sizes; (void)n_in; (void)out_size;

  // prep: weight transposes + router (one launch)
  prep_kernel<<<15360 + 2048, 256, 0, stream>>>(
      x, wt, g, wg, w_gate, w_up, w_down, sw_gate, sw_up, sw_down,
      wg_t, wu_t, wd_t, swg_t, swu_t, swd_t, xb, tidx, tw);
  hist_kernel<<<NBLK_PLACE, 256, 0, stream>>>(tidx, bcount);
  scan2_kernel<<<1, 64, 0, stream>>>(bcount, boffs, offs, desc, ndesc);
  place2_kernel<<<NBLK_PLACE, 256, 0, stream>>>(tidx, boffs, perm, slot_of);

  // fused gate/up duals (shared + routed in one launch)
  gemm_dual_all<<<256 + MAX_TILES * 4, 512, 0, stream>>>(
      xb, swg_t, swu_t, hsh, wg_t, wu_t, h_e, perm, desc, ndesc);
  // down projections (shared -> ysh bf16, routed -> ye bf16, one launch)
  gemm_down_all<<<128 + MAX_TILES * 4, 512, 0, stream>>>(
      hsh, swd_t, ysh, h_e, wd_t, ye, desc, ndesc);

  // combine
  final_kernel<<<2048, 256, 0, stream>>>(y, ysh, ye, slot_of, tw);
}